// Round 8
// baseline (1479.318 us; speedup 1.0000x reference)
//
#include <hip/hip_runtime.h>
#include <hip/hip_bf16.h>
#include <stdint.h>

// ---------------------------------------------------------------------------
// MotionVAE, round 8: vae_dec MoE loop rebuilt — kb fully unrolled
// (compile-time ds_read immediate offsets, no int division, compile-time
// acc-zero/coef-fold), A-prefetch double-buffer (parity-indexed, static),
// B pointer-bump addressing. vae_enc unchanged.
// ---------------------------------------------------------------------------

#define NB 65536
#define CHUNK 8192   // enc activation chunk: [128][32] bf16
#define CH64  4096   // dec activation chunk: [64][32] bf16

typedef __attribute__((ext_vector_type(8))) short bf16x8;
typedef __attribute__((ext_vector_type(4))) float f32x4;

union FragU { bf16x8 v; unsigned int w[4]; uint4 u4; };

// ---- workspace byte offsets ----
#define WP_E1   0
#define WP_E2   262144
#define WP_MULV 393216
#define WP_G1   458752
#define WP_G2   499712
#define WP_G3   507904
#define WP_DEC  509952     // 4 x 6 x 10 x 16384 B
#define WP_BDEC 4442112    // f32 [4][6][256]
#define WP_COEF 4466688    // f32 [512 enc-blocks][768]

// ---- LDS offsets, encoder kernel (unchanged) ----
#define L_XN     0
#define L_SCR    81920
#define L_WB     98304
#define LDS_ENC  147456
#define L_MUF   (L_XN + 2*CHUNK)
#define L_LVF   L_WB
#define L_HG1   L_WB
#define L_HG2   (L_WB + 32768)
#define L_G2W   L_SCR
#define L_G3W   (L_SCR + 8192)
#define L_SCORE (L_SCR + 10240)

// ---- LDS offsets, decoder kernel (64-row) ----
#define D_XN     0          // 10 x 4096 = 40960
#define D_COEF   40960      // f32 [6][64] = 1536
#define D_STATS  42496      // f32 [64][2] = 512
#define D_PART   43008      // f32 [64][8][2] = 4096
#define D_PARTMU 47104      // f32 [64][8][2] = 4096
#define D_MUSTAT 51200      // f32 [64][2] = 512
#define LDS_DEC  51712

__device__ __forceinline__ unsigned int pack2(float a, float b){
    __hip_bfloat162 h = __float22bfloat162_rn(make_float2(a, b));
    union { __hip_bfloat162 h2; unsigned int u; } cv; cv.h2 = h; return cv.u;
}
__device__ __forceinline__ unsigned short f2bf(float a){
    __hip_bfloat16 h = __float2bfloat16(a);
    union { __hip_bfloat16 h1; unsigned short u; } cv; cv.h1 = h; return cv.u;
}
__device__ __forceinline__ float eluf(float x){ return x > 0.f ? x : expm1f(x); }
__device__ __forceinline__ f32x4 mfma16(bf16x8 a, bf16x8 b, f32x4 c){
    return __builtin_amdgcn_mfma_f32_16x16x32_bf16(a, b, c, 0, 0, 0);
}
__device__ __forceinline__ void gload16(const void* g, void* l){
    __builtin_amdgcn_global_load_lds(
        (__attribute__((address_space(1))) unsigned int*)(uintptr_t)g,
        (__attribute__((address_space(3))) unsigned int*)(unsigned int)(uintptr_t)l,
        16, 0, 0);
}

template<int N> __device__ __forceinline__ void pipeV(){
    __builtin_amdgcn_sched_barrier(0);
    asm volatile("s_waitcnt vmcnt(%0)" :: "n"(N) : "memory");
    asm volatile("s_barrier" ::: "memory");
    __builtin_amdgcn_sched_barrier(0);
}
template<int N> __device__ __forceinline__ void pipeVL(){
    __builtin_amdgcn_sched_barrier(0);
    asm volatile("s_waitcnt vmcnt(%0) lgkmcnt(0)" :: "n"(N) : "memory");
    asm volatile("s_barrier" ::: "memory");
    __builtin_amdgcn_sched_barrier(0);
}
__device__ __forceinline__ void pipeL(){
    __builtin_amdgcn_sched_barrier(0);
    asm volatile("s_waitcnt lgkmcnt(0)" ::: "memory");
    asm volatile("s_barrier" ::: "memory");
    __builtin_amdgcn_sched_barrier(0);
}

// ---------------------------------------------------------------------------
// pack kernels (unchanged)
// ---------------------------------------------------------------------------
__global__ void pack_small(const float* __restrict__ e1w, const float* __restrict__ e2w,
                           const float* __restrict__ muw, const float* __restrict__ lvw,
                           const float* __restrict__ g1w, const float* __restrict__ g2w,
                           const float* __restrict__ g3w, unsigned short* __restrict__ wsh){
    int p = blockIdx.x*256 + threadIdx.x;   // < 254976
    int local, k, n;
    auto decode = [&](int base, int NN){
        local = p - base;
        int i = local & 7, ln = (local>>3)&63, rest = local>>9;
        int ntg = rest % (NN/16), kb = rest / (NN/16);
        k = kb*32 + (ln>>4)*8 + i; n = ntg*16 + (ln&15);
    };
    if (p < 131072)      { decode(0,      256); wsh[WP_E1/2   + local] = f2bf(e1w[k*256+n]); }
    else if (p < 196608) { decode(131072, 256); wsh[WP_E2/2   + local] = f2bf(e2w[k*256+n]); }
    else if (p < 229376) { decode(196608, 128); wsh[WP_MULV/2 + local] = f2bf(n < 64 ? muw[k*64+n] : lvw[k*64+n-64]); }
    else if (p < 249856) { decode(229376,  64); wsh[WP_G1/2   + local] = f2bf(g1w[k*64+n]); }
    else if (p < 253952) { decode(249856,  64); wsh[WP_G2/2   + local] = f2bf(g2w[k*64+n]); }
    else                 { decode(253952,  16); wsh[WP_G3/2   + local] = f2bf(n < 6 ? g3w[k*6+n] : 0.f); }
}

__global__ void pack_dec(const float* __restrict__ w0, const float* __restrict__ w1,
                         const float* __restrict__ w2, const float* __restrict__ w3,
                         const float* __restrict__ s0, const float* __restrict__ s1,
                         const float* __restrict__ s2, const float* __restrict__ s3,
                         unsigned short* __restrict__ wsh){
    int p = blockIdx.x*256 + threadIdx.x;   // < 1966080
    int i = p & 7, ln = (p>>3)&63, rest = p>>9;
    int ntg = rest & 15, r2 = rest >> 4;
    int kb = r2 % 10, r3 = r2 / 10;
    int e = r3 % 6, L = r3 / 6;
    int k = kb*32 + (ln>>4)*8 + i;
    int n = ntg*16 + (ln&15);
    const float* w = (L==0)?w0:(L==1)?w1:(L==2)?w2:w3;
    const float* s = (L==0)?s0:(L==1)?s1:(L==2)?s2:s3;
    wsh[WP_DEC/2 + p] = f2bf(s[k] * w[(e*320+k)*256 + n]);
}

__global__ void pack_bdec(const float* __restrict__ w0, const float* __restrict__ w1,
                          const float* __restrict__ w2, const float* __restrict__ w3,
                          const float* __restrict__ b0, const float* __restrict__ b1,
                          const float* __restrict__ b2, const float* __restrict__ b3,
                          const float* __restrict__ t0, const float* __restrict__ t1,
                          const float* __restrict__ t2, const float* __restrict__ t3,
                          float* __restrict__ outp){
    int t = blockIdx.x*256 + threadIdx.x;   // < 6144
    int n = t & 255, r = t >> 8;
    int e = r % 6, L = r / 6;
    const float* w  = (L==0)?w0:(L==1)?w1:(L==2)?w2:w3;
    const float* b  = (L==0)?b0:(L==1)?b1:(L==2)?b2:b3;
    const float* lb = (L==0)?t0:(L==1)?t1:(L==2)?t2:t3;
    float acc = b[e*256 + n];
    for (int k = 0; k < 320; ++k) acc += lb[k] * w[(e*320+k)*256 + n];
    outp[(L*6+e)*256 + n] = acc;
}

// ---------------------------------------------------------------------------
// vae_enc (unchanged): encoder + reparam + gating.
// ---------------------------------------------------------------------------
__global__ __launch_bounds__(512, 2) void vae_enc(
    const float* __restrict__ curr, const float* __restrict__ nxt,
    const float* __restrict__ eps,
    const float* __restrict__ eb1, const float* __restrict__ eb2,
    const float* __restrict__ mub, const float* __restrict__ lvb,
    const float* __restrict__ gb1, const float* __restrict__ gb2,
    const float* __restrict__ gb3,
    const unsigned short* __restrict__ wsh,
    float* __restrict__ coefws, float* __restrict__ dout)
{
    __shared__ __align__(16) char sm[LDS_ENC];
    const int tid  = threadIdx.x;
    const int lane = tid & 63;
    const int wave = tid >> 6;
    const int wr   = wave >> 2;
    const int wc   = wave & 3;
    const int l15  = lane & 15;
    const int lh   = lane >> 4;
    const long row0 = (long)blockIdx.x * 128;
    const char* wsb = (const char*)wsh;
    const f32x4 Z4 = {0.f, 0.f, 0.f, 0.f};

    const int aswz = ((lh ^ ((l15 >> 1) & 3)) << 4);
    int aoff[4];
    #pragma unroll
    for (int mt = 0; mt < 4; ++mt)
        aoff[mt] = ((((wr << 6) + (mt << 4) + l15)) << 6) + aswz;

    auto WB = [&](int i) -> int { return L_WB + i*16384; };
    auto stage16 = [&](long gOff, int ldsBase){
        gload16(wsb + gOff + ((long)wave << 10) + (lane << 4), sm + ldsBase + (wave << 10));
        gload16(wsb + gOff + ((long)(wave + 8) << 10) + (lane << 4), sm + ldsBase + ((wave + 8) << 10));
    };
    auto stage8 = [&](long gOff, int ldsBase){
        gload16(wsb + gOff + ((long)wave << 10) + (lane << 4), sm + ldsBase + (wave << 10));
    };
    auto stage4 = [&](long gOff, int ldsBase){
        int u = wave & 3;
        gload16(wsb + gOff + ((long)u << 10) + (lane << 4), sm + ldsBase + (u << 10));
    };
    auto loadB = [&](int bufBase, int idx) -> bf16x8 {
        FragU f; f.u4 = *(const uint4*)(sm + bufBase + (idx << 10) + (lane << 4));
        return f.v;
    };
    auto putRow = [&](int base, int n, int mt, const f32x4& v){
        char* cb = sm + base + ((n >> 5) * CHUNK);
        int col = n & 31;
        #pragma unroll
        for (int j = 0; j < 4; ++j){
            int r = (wr << 6) + (mt << 4) + (lh << 2) + j;
            *(unsigned short*)(cb + (r << 6) + ((((col >> 3) ^ ((r >> 1) & 3))) << 4)
                               + ((col & 7) << 1)) = f2bf(v[j]);
        }
    };

    f32x4 acc4[4][4];
    // ===== encoder layer 1 =====
    #pragma unroll
    for (int a = 0; a < 4; ++a)
        #pragma unroll
        for (int b = 0; b < 4; ++b) acc4[a][b] = Z4;
    {
        const int xrow = tid >> 2, xg = tid & 3;
        float4 xa, xb;
        auto loadX = [&](int kb){
            const float* src = (kb < 8) ? curr : nxt;
            const float* p = src + (row0 + xrow)*256 + (kb & 7)*32 + xg*8;
            xa = *(const float4*)p; xb = *(const float4*)(p + 4);
        };
        auto packX = [&](int slot){
            uint4 pk;
            pk.x = pack2(xa.x, xa.y); pk.y = pack2(xa.z, xa.w);
            pk.z = pack2(xb.x, xb.y); pk.w = pack2(xb.z, xb.w);
            *(uint4*)(sm + L_XN + slot*CHUNK + (xrow << 6)
                      + ((xg ^ ((xrow >> 1) & 3)) << 4)) = pk;
        };
        stage16(WP_E1, WB(0)); stage16(WP_E1 + 16384, WB(1));
        loadX(0); packX(0);
        loadX(1);
        #pragma unroll 1
        for (int s = 0; s < 16; ++s){
            pipeVL<4>();
            if (s + 2 < 16) stage16(WP_E1 + (long)(s + 2)*16384, WB((s + 2) % 3));
            if (s + 1 < 16){
                packX((s + 1) & 1);
                if (s + 2 < 16) loadX(s + 2);
            }
            int xbuf = L_XN + (s & 1)*CHUNK;
            int wb = WB(s % 3);
            FragU a[4];
            #pragma unroll
            for (int mt = 0; mt < 4; ++mt) a[mt].u4 = *(const uint4*)(sm + xbuf + aoff[mt]);
            #pragma unroll
            for (int nt = 0; nt < 4; ++nt){
                bf16x8 b = loadB(wb, wc*4 + nt);
                #pragma unroll
                for (int mt = 0; mt < 4; ++mt) acc4[mt][nt] = mfma16(a[mt].v, b, acc4[mt][nt]);
            }
        }
        pipeL();
        #pragma unroll
        for (int nt = 0; nt < 4; ++nt){
            int n = wc*64 + nt*16 + l15;
            float bias = eb1[n];
            #pragma unroll
            for (int mt = 0; mt < 4; ++mt){
                f32x4 v;
                #pragma unroll
                for (int j = 0; j < 4; ++j) v[j] = eluf(acc4[mt][nt][j] + bias);
                putRow(L_XN, n, mt, v);
            }
        }
        stage16(WP_E2, WB(0)); stage16(WP_E2 + 16384, WB(1));
        pipeL();
    }
    // ===== encoder layer 2 =====
    #pragma unroll
    for (int a = 0; a < 4; ++a)
        #pragma unroll
        for (int b = 0; b < 4; ++b) acc4[a][b] = Z4;
    {
        #pragma unroll 1
        for (int s = 0; s < 8; ++s){
            if (s + 1 < 8) pipeV<2>(); else pipeV<0>();
            if (s + 2 < 8) stage16(WP_E2 + (long)(s + 2)*16384, WB((s + 2) % 3));
            int wb = WB(s % 3);
            FragU a[4];
            #pragma unroll
            for (int mt = 0; mt < 4; ++mt)
                a[mt].u4 = *(const uint4*)(sm + L_XN + s*CHUNK + aoff[mt]);
            #pragma unroll
            for (int nt = 0; nt < 4; ++nt){
                bf16x8 b = loadB(wb, wc*4 + nt);
                #pragma unroll
                for (int mt = 0; mt < 4; ++mt) acc4[mt][nt] = mfma16(a[mt].v, b, acc4[mt][nt]);
            }
        }
        pipeL();
        #pragma unroll
        for (int nt = 0; nt < 4; ++nt){
            int n = wc*64 + nt*16 + l15;
            float bias = eb2[n];
            #pragma unroll
            for (int mt = 0; mt < 4; ++mt){
                f32x4 v;
                #pragma unroll
                for (int j = 0; j < 4; ++j) v[j] = eluf(acc4[mt][nt][j] + bias);
                putRow(L_XN, n, mt, v);
            }
        }
        stage8(WP_MULV, WB(0)); stage8(WP_MULV + 8192, WB(1));
        pipeL();
    }
    // ===== mu | logvar =====
    {
        f32x4 am[4][2];
        #pragma unroll
        for (int a = 0; a < 4; ++a){ am[a][0] = Z4; am[a][1] = Z4; }
        #pragma unroll 1
        for (int s = 0; s < 8; ++s){
            if (s + 1 < 8) pipeV<1>(); else pipeV<0>();
            if (s + 2 < 8) stage8(WP_MULV + (long)(s + 2)*8192, WB((s + 2) % 3));
            int wb = WB(s % 3);
            FragU a[4];
            #pragma unroll
            for (int mt = 0; mt < 4; ++mt)
                a[mt].u4 = *(const uint4*)(sm + L_XN + s*CHUNK + aoff[mt]);
            #pragma unroll
            for (int nt = 0; nt < 2; ++nt){
                bf16x8 b = loadB(wb, wc*2 + nt);
                #pragma unroll
                for (int mt = 0; mt < 4; ++mt) am[mt][nt] = mfma16(a[mt].v, b, am[mt][nt]);
            }
        }
        pipeL();
        #pragma unroll
        for (int nt = 0; nt < 2; ++nt){
            int n = wc*32 + nt*16 + l15;
            if (n < 64){
                float bias = mub[n];
                #pragma unroll
                for (int mt = 0; mt < 4; ++mt)
                    #pragma unroll
                    for (int j = 0; j < 4; ++j){
                        int r = (wr << 6) + (mt << 4) + (lh << 2) + j;
                        float v = am[mt][nt][j] + bias;
                        *(float*)(sm + L_MUF + (r << 8) + (n << 2)) = v;
                        dout[(long)NB*320 + (row0 + r)*64 + n] = v;
                    }
            } else {
                float bias = lvb[n - 64];
                #pragma unroll
                for (int mt = 0; mt < 4; ++mt)
                    #pragma unroll
                    for (int j = 0; j < 4; ++j){
                        int r = (wr << 6) + (mt << 4) + (lh << 2) + j;
                        float v = am[mt][nt][j] + bias;
                        *(float*)(sm + L_LVF + (r << 8) + ((n - 64) << 2)) = v;
                        dout[(long)NB*384 + (row0 + r)*64 + (n - 64)] = v;
                    }
            }
        }
        pipeL();
    }
    // ===== z =====
    {
        int row = tid >> 2, seg = (tid & 3) << 4;
        float zm[16], zl[16];
        #pragma unroll
        for (int q = 0; q < 4; ++q){
            float4 m4 = *(const float4*)(sm + L_MUF + (row << 8) + ((seg + q*4) << 2));
            float4 l4 = *(const float4*)(sm + L_LVF + (row << 8) + ((seg + q*4) << 2));
            zm[q*4+0]=m4.x; zm[q*4+1]=m4.y; zm[q*4+2]=m4.z; zm[q*4+3]=m4.w;
            zl[q*4+0]=l4.x; zl[q*4+1]=l4.y; zl[q*4+2]=l4.z; zl[q*4+3]=l4.w;
        }
        const float* ep = eps + (row0 + row)*64 + seg;
        float* zo = dout + (long)NB*256 + (row0 + row)*64 + seg;
        #pragma unroll
        for (int q = 0; q < 4; ++q){
            float4 e4 = *(const float4*)(ep + q*4);
            float4 z4;
            z4.x = zm[q*4+0] + e4.x * expf(0.5f*zl[q*4+0]);
            z4.y = zm[q*4+1] + e4.y * expf(0.5f*zl[q*4+1]);
            z4.z = zm[q*4+2] + e4.z * expf(0.5f*zl[q*4+2]);
            z4.w = zm[q*4+3] + e4.w * expf(0.5f*zl[q*4+3]);
            *(float4*)(zo + q*4) = z4;
        }
        uint4 pkA, pkB;
        pkA.x = pack2(zm[0],  zm[1]);  pkA.y = pack2(zm[2],  zm[3]);
        pkA.z = pack2(zm[4],  zm[5]);  pkA.w = pack2(zm[6],  zm[7]);
        pkB.x = pack2(zm[8],  zm[9]);  pkB.y = pack2(zm[10], zm[11]);
        pkB.z = pack2(zm[12], zm[13]); pkB.w = pack2(zm[14], zm[15]);
        int c = seg >> 5, g0 = (seg & 31) >> 3, sw = (row >> 1) & 3;
        char* cb = sm + L_XN + c*CHUNK + (row << 6);
        *(uint4*)(cb + ((g0 ^ sw) << 4))       = pkA;
        *(uint4*)(cb + (((g0 + 1) ^ sw) << 4)) = pkB;
    }
    pipeL();
    // ===== curr -> XN chunks 2..9; G1 prologue =====
    #pragma unroll
    for (int c = 0; c < 2; ++c){
        int idx = c*512 + tid;
        int row = idx & 127, kbi = idx >> 7;
        const float* p = curr + (row0 + row)*256 + kbi*32;
        char* cb = sm + L_XN + (2 + kbi)*CHUNK + (row << 6);
        int sw = (row >> 1) & 3;
        #pragma unroll
        for (int g = 0; g < 4; ++g){
            float4 fa = *(const float4*)(p + g*8);
            float4 fb = *(const float4*)(p + g*8 + 4);
            uint4 pk;
            pk.x = pack2(fa.x, fa.y); pk.y = pack2(fa.z, fa.w);
            pk.z = pack2(fb.x, fb.y); pk.w = pack2(fb.z, fb.w);
            *(uint4*)(cb + ((g ^ sw) << 4)) = pk;
        }
    }
    stage4(WP_G1, WB(0)); stage4(WP_G1 + 4096, WB(1));
    pipeL();
    // ===== gating MLP =====
    {
        f32x4 ga[4];
        #pragma unroll
        for (int a = 0; a < 4; ++a) ga[a] = Z4;
        #pragma unroll 1
        for (int s = 0; s < 10; ++s){
            if (s + 1 < 10) pipeV<1>(); else pipeV<0>();
            if (s + 2 < 10) stage4(WP_G1 + (long)(s + 2)*4096, WB((s + 2) % 3));
            int wb = WB(s % 3);
            bf16x8 b = loadB(wb, wc);
            #pragma unroll
            for (int mt = 0; mt < 4; ++mt){
                FragU a; a.u4 = *(const uint4*)(sm + L_XN + s*CHUNK + aoff[mt]);
                ga[mt] = mfma16(a.v, b, ga[mt]);
            }
        }
        pipeL();
        {
            int n = wc*16 + l15;
            float bias = gb1[n];
            #pragma unroll
            for (int mt = 0; mt < 4; ++mt){
                f32x4 v;
                #pragma unroll
                for (int j = 0; j < 4; ++j) v[j] = eluf(ga[mt][j] + bias);
                putRow(L_HG1, n, mt, v);
            }
        }
        stage8(WP_G2, L_G2W);
        if (wave < 2)
            gload16(wsb + WP_G3 + ((long)wave << 10) + (lane << 4),
                    sm + L_G3W + (wave << 10));
        pipeVL<0>();
        // G2
        #pragma unroll
        for (int a = 0; a < 4; ++a) ga[a] = Z4;
        #pragma unroll
        for (int kb = 0; kb < 2; ++kb){
            bf16x8 b = loadB(L_G2W, kb*4 + wc);
            #pragma unroll
            for (int mt = 0; mt < 4; ++mt){
                FragU a; a.u4 = *(const uint4*)(sm + L_HG1 + kb*CHUNK + aoff[mt]);
                ga[mt] = mfma16(a.v, b, ga[mt]);
            }
        }
        pipeL();
        {
            int n = wc*16 + l15;
            float bias = gb2[n];
            #pragma unroll
            for (int mt = 0; mt < 4; ++mt){
                f32x4 v;
                #pragma unroll
                for (int j = 0; j < 4; ++j) v[j] = eluf(ga[mt][j] + bias);
                putRow(L_HG2, n, mt, v);
            }
        }
        pipeL();
        // G3
        if (wc == 0){
            f32x4 sc[4];
            #pragma unroll
            for (int a = 0; a < 4; ++a) sc[a] = Z4;
            #pragma unroll
            for (int kb = 0; kb < 2; ++kb){
                bf16x8 b = loadB(L_G3W, kb);
                #pragma unroll
                for (int mt = 0; mt < 4; ++mt){
                    FragU a; a.u4 = *(const uint4*)(sm + L_HG2 + kb*CHUNK + aoff[mt]);
                    sc[mt] = mfma16(a.v, b, sc[mt]);
                }
            }
            if (l15 < 8){
                float bias = (l15 < 6) ? gb3[l15] : 0.f;
                #pragma unroll
                for (int mt = 0; mt < 4; ++mt)
                    #pragma unroll
                    for (int j = 0; j < 4; ++j){
                        int r = (wr << 6) + (mt << 4) + (lh << 2) + j;
                        *(float*)(sm + L_SCORE + (r << 5) + (l15 << 2)) = sc[mt][j] + bias;
                    }
            }
        }
        pipeL();
        if (tid < 128){
            float s[6];
            #pragma unroll
            for (int e = 0; e < 6; ++e) s[e] = *(const float*)(sm + L_SCORE + (tid << 5) + (e << 2));
            float m = s[0];
            #pragma unroll
            for (int e = 1; e < 6; ++e) m = fmaxf(m, s[e]);
            float sum = 0.f;
            #pragma unroll
            for (int e = 0; e < 6; ++e){ s[e] = expf(s[e] - m); sum += s[e]; }
            float inv = 1.f / sum;
            float* cw = coefws + (long)blockIdx.x * 768;
            #pragma unroll
            for (int e = 0; e < 6; ++e) cw[e*128 + tid] = s[e] * inv;
        }
    }
}

// ---------------------------------------------------------------------------
// vae_dec: 64-row blocks x 512 threads (8 waves), wave w owns 64 rows x
// 32 cols. MoE loop: kb fully unrolled (immediate ds offsets, compile-time
// acc-zero/fold), A-prefetch dbuf (parity static), B pointer-bump dbuf.
// ---------------------------------------------------------------------------
__global__ __launch_bounds__(512, 4) void vae_dec(
    const float* __restrict__ curr,
    const unsigned short* __restrict__ wsh, const float* __restrict__ bdec,
    const float* __restrict__ coefws, float* __restrict__ dout)
{
    __shared__ __align__(16) char sm[LDS_DEC];
    const int tid  = threadIdx.x;
    const int lane = tid & 63;
    const int w    = tid >> 6;          // 0..7 column group (32 cols)
    const int l15  = lane & 15;
    const int lh   = lane >> 4;
    const long row0 = (long)blockIdx.x * 64;
    const int eb   = blockIdx.x >> 1, half = blockIdx.x & 1;
    const char* wsb = (const char*)wsh;
    const f32x4 Z4 = {0.f, 0.f, 0.f, 0.f};

    const int aswz = ((lh ^ ((l15 >> 1) & 3)) << 4);
    int aoff[4];
    #pragma unroll
    for (int mt = 0; mt < 4; ++mt)
        aoff[mt] = (((mt << 4) + l15) << 6) + aswz;

    auto putRow = [&](int base, int n, int mt, const f32x4& v){
        char* cb = sm + base + ((n >> 5) * CH64);
        int col = n & 31;
        #pragma unroll
        for (int j = 0; j < 4; ++j){
            int r = (mt << 4) + (lh << 2) + j;
            *(unsigned short*)(cb + (r << 6) + ((((col >> 3) ^ ((r >> 1) & 3))) << 4)
                               + ((col & 7) << 1)) = f2bf(v[j]);
        }
    };

    // ---- coef: [6][64] for this block's row half ----
    if (tid < 384)
        *(float*)(sm + D_COEF + (tid << 2)) =
            coefws[(long)eb*768 + (tid >> 6)*128 + half*64 + (tid & 63)];
    // ---- raw mu (f32 in dout) -> XN chunks 0,1 ----
    {
        int row = tid >> 3, seg = (tid & 7) << 3;
        const float* mp = dout + (long)NB*320 + (row0 + row)*64 + seg;
        float4 a4 = *(const float4*)mp;
        float4 b4 = *(const float4*)(mp + 4);
        uint4 pk;
        pk.x = pack2(a4.x, a4.y); pk.y = pack2(a4.z, a4.w);
        pk.z = pack2(b4.x, b4.y); pk.w = pack2(b4.z, b4.w);
        int g0 = seg >> 3, c = g0 >> 2, gg = g0 & 3, sw = (row >> 1) & 3;
        *(uint4*)(sm + D_XN + c*CH64 + (row << 6) + ((gg ^ sw) << 4)) = pk;
    }
    // ---- curr -> XN chunks 2..9 ----
    {
        int row = tid & 63, kbi = tid >> 6;
        const float* p = curr + (row0 + row)*256 + kbi*32;
        char* cb = sm + D_XN + (2 + kbi)*CH64 + (row << 6);
        int sw = (row >> 1) & 3;
        #pragma unroll
        for (int g = 0; g < 4; ++g){
            float4 fa = *(const float4*)(p + g*8);
            float4 fb = *(const float4*)(p + g*8 + 4);
            uint4 pk;
            pk.x = pack2(fa.x, fa.y); pk.y = pack2(fa.z, fa.w);
            pk.z = pack2(fb.x, fb.y); pk.w = pack2(fb.z, fb.w);
            *(uint4*)(cb + ((g ^ sw) << 4)) = pk;
        }
    }
    __syncthreads();
    // ---- layer-0 LN stats ----
    {
        int row = tid >> 3, part = tid & 7;
        int sw = (row >> 1) & 3;
        float s = 0.f, q = 0.f, smu = 0.f, qmu = 0.f;
        #pragma unroll
        for (int k = 0; k < 5; ++k){
            int g = part + (k << 3);
            int c = g >> 2, gg = g & 3;
            uint4 d = *(const uint4*)(sm + D_XN + c*CH64 + (row << 6) + ((gg ^ sw) << 4));
            const unsigned int* dw = (const unsigned int*)&d;
            float ls = 0.f, lq = 0.f;
            #pragma unroll
            for (int u = 0; u < 4; ++u){
                float lo = __uint_as_float(dw[u] << 16);
                float hi = __uint_as_float(dw[u] & 0xffff0000u);
                ls += lo + hi; lq += lo*lo + hi*hi;
            }
            s += ls; q += lq;
            if (k == 0){ smu = ls; qmu = lq; }
        }
        *(float2*)(sm + D_PART   + (((row << 3) + part) << 3)) = make_float2(s, q);
        *(float2*)(sm + D_PARTMU + (((row << 3) + part) << 3)) = make_float2(smu, qmu);
    }
    __syncthreads();
    if (tid < 64){
        float S = 0.f, Q = 0.f, Sm = 0.f, Qm = 0.f;
        #pragma unroll
        for (int pp = 0; pp < 8; ++pp){
            float2 f = *(const float2*)(sm + D_PART   + (((tid << 3) + pp) << 3));
            float2 g = *(const float2*)(sm + D_PARTMU + (((tid << 3) + pp) << 3));
            S += f.x; Q += f.y; Sm += g.x; Qm += g.y;
        }
        float mean = S * (1.f/320.f);
        float var  = Q * (1.f/320.f) - mean*mean;
        *(float2*)(sm + D_STATS  + (tid << 3)) = make_float2(mean, rsqrtf(var + 1e-5f));
        *(float2*)(sm + D_MUSTAT + (tid << 3)) = make_float2(Sm, Qm);
    }
    __syncthreads();
    {   // normalize all 10 chunks in place
        int row = tid >> 3, part = tid & 7;
        int sw = (row >> 1) & 3;
        float2 st = *(const float2*)(sm + D_STATS + (row << 3));
        #pragma unroll
        for (int k = 0; k < 5; ++k){
            int g = part + (k << 3);
            int c = g >> 2, gg = g & 3;
            char* p = sm + D_XN + c*CH64 + (row << 6) + ((gg ^ sw) << 4);
            uint4 d = *(const uint4*)p;
            const unsigned int* dw = (const unsigned int*)&d;
            uint4 o; unsigned int* ow = (unsigned int*)&o;
            #pragma unroll
            for (int u = 0; u < 4; ++u){
                float lo = (__uint_as_float(dw[u] << 16)         - st.x) * st.y;
                float hi = (__uint_as_float(dw[u] & 0xffff0000u) - st.x) * st.y;
                ow[u] = pack2(lo, hi);
            }
            *(uint4*)p = o;
        }
    }
    __syncthreads();

    // ---- 4 MoE layers ----
    f32x4 master[4][2], acc[4][2];
    #pragma unroll
    for (int a = 0; a < 4; ++a){ master[a][0] = Z4; master[a][1] = Z4; }

    #pragma unroll 1
    for (int L = 0; L < 4; ++L){
        const char* wp = wsb + WP_DEC + (((long)L*60) << 14) + (lane << 4)
                         + ((w*2) << 10);
        FragU aBuf[2][4], bBuf[2][2];
        // prologue: B(e=0,kb=0) and A(kb=0) into parity slot 0
        bBuf[0][0].u4 = *(const uint4*)(wp);
        bBuf[0][1].u4 = *(const uint4*)(wp + 1024);
        wp += 16384;
        #pragma unroll
        for (int mt = 0; mt < 4; ++mt)
            aBuf[0][mt].u4 = *(const uint4*)(sm + D_XN + aoff[mt]);

        #pragma unroll 1
        for (int e = 0; e < 6; ++e){
            const float* cqp = (const float*)(sm + D_COEF) + (e << 6);
            #pragma unroll
            for (int kb = 0; kb < 10; ++kb){
                const int cur = kb & 1, nxt = cur ^ 1;
                // prefetch next B (final iteration reads dead-but-valid bytes)
                bBuf[nxt][0].u4 = *(const uint4*)(wp);
                bBuf[nxt][1].u4 = *(const uint4*)(wp + 1024);
                wp += 16384;
                // prefetch next A (kb+1, or kb=0 for the next expert)
                const int nkb = (kb == 9) ? 0 : kb + 1;
                #pragma unroll
                for (int mt = 0; mt < 4; ++mt)
                    aBuf[nxt][mt].u4 = *(const uint4*)(sm + D_XN + nkb*CH64 + aoff[mt]);
                // MFMAs on current (compile-time acc-zero at kb==0)
                #pragma unroll
                for (int nt = 0; nt < 2; ++nt)
                    #pragma unroll
                    for (int mt = 0; mt < 4; ++mt)
                        acc[mt][nt] = mfma16(aBuf[cur][mt].v, bBuf[cur][nt].v,
                                             (kb == 0) ? Z4 : acc[mt][nt]);
                if (kb == 9){   // fold: master += coef_e[row] * acc
                    #pragma unroll
                    for (int mt = 0; mt < 4; ++mt){
                        f32x4 cq = *(const f32x4*)(cqp + (mt << 4) + (lh << 2));
                        #pragma unroll
                        for (int nt = 0; nt < 2; ++nt)
                            #pragma unroll
                            for (int j = 0; j < 4; ++j)
                                master[mt][nt][j] = fmaf(cq[j], acc[mt][nt][j],
                                                         master[mt][nt][j]);
                    }
                }
            }
        }
        __syncthreads();

        // ---- epilogue ----
        {
            float bv[6][2];
            #pragma unroll
            for (int ee = 0; ee < 6; ++ee)
                #pragma unroll
                for (int nt = 0; nt < 2; ++nt)
                    bv[ee][nt] = bdec[((L*6 + ee) << 8) + w*32 + nt*16 + l15];
            #pragma unroll
            for (int mt = 0; mt < 4; ++mt){
                f32x4 cq[6];
                #pragma unroll
                for (int ee = 0; ee < 6; ++ee)
                    cq[ee] = *(const f32x4*)(sm + D_COEF +
                              ((ee*64 + (mt << 4) + (lh << 2)) << 2));
                #pragma unroll
                for (int nt = 0; nt < 2; ++nt){
                    int n = w*32 + nt*16 + l15;
                    f32x4 v;
                    #pragma unroll
                    for (int j = 0; j < 4; ++j){
                        float bias = cq[0][j]*bv[0][nt] + cq[1][j]*bv[1][nt]
                                   + cq[2][j]*bv[2][nt] + cq[3][j]*bv[3][nt]
                                   + cq[4][j]*bv[4][nt] + cq[5][j]*bv[5][nt];
                        float mix = master[mt][nt][j] + bias;
                        v[j] = (L == 3) ? mix : eluf(mix);
                    }
                    if (L < 3){
                        acc[mt][nt] = v;
                        master[mt][nt] = (L < 2) ? v : Z4;
                    } else {
                        #pragma unroll
                        for (int j = 0; j < 4; ++j){
                            int r = (mt << 4) + (lh << 2) + j;
                            dout[(row0 + r)*256 + n] = v[j];
                        }
                    }
                }
            }
        }
        if (L < 3){
            // ---- next-layer LN stats: shuffle reduce over out tile ----
            #pragma unroll
            for (int mt = 0; mt < 4; ++mt){
                f32x4 sv = acc[mt][0] + acc[mt][1];
                f32x4 qv = acc[mt][0]*acc[mt][0] + acc[mt][1]*acc[mt][1];
                #pragma unroll
                for (int x = 1; x < 16; x <<= 1){
                    #pragma unroll
                    for (int j = 0; j < 4; ++j){
                        sv[j] += __shfl_xor(sv[j], x);
                        qv[j] += __shfl_xor(qv[j], x);
                    }
                }
                if (l15 == 0){
                    #pragma unroll
                    for (int j = 0; j < 4; ++j){
                        int r = (mt << 4) + (lh << 2) + j;
                        *(float2*)(sm + D_PART + (((r << 3) + w) << 3)) = make_float2(sv[j], qv[j]);
                    }
                }
            }
            __syncthreads();
            if (tid < 64){
                float2 mu2 = *(const float2*)(sm + D_MUSTAT + (tid << 3));
                float S = mu2.x, Q = mu2.y;
                #pragma unroll
                for (int pp = 0; pp < 8; ++pp){
                    float2 f = *(const float2*)(sm + D_PART + (((tid << 3) + pp) << 3));
                    S += f.x; Q += f.y;
                }
                float mean = S * (1.f/320.f);
                float var  = Q * (1.f/320.f) - mean*mean;
                *(float2*)(sm + D_STATS + (tid << 3)) = make_float2(mean, rsqrtf(var + 1e-5f));
            }
            __syncthreads();
            // ---- write normalized out -> XN chunks 2..9 (from registers) ----
            #pragma unroll
            for (int mt = 0; mt < 4; ++mt){
                int r0 = (mt << 4) + (lh << 2);
                float4 p0 = *(const float4*)(sm + D_STATS + (r0 << 3));
                float4 p1 = *(const float4*)(sm + D_STATS + (r0 << 3) + 16);
                float mj[4] = {p0.x, p0.z, p1.x, p1.z};
                float rj[4] = {p0.y, p0.w, p1.y, p1.w};
                #pragma unroll
                for (int nt = 0; nt < 2; ++nt){
                    int n = w*32 + nt*16 + l15;
                    f32x4 xn;
                    #pragma unroll
                    for (int j = 0; j < 4; ++j) xn[j] = (acc[mt][nt][j] - mj[j]) * rj[j];
                    putRow(D_XN + 2*CH64, n, mt, xn);
                }
            }
            // ---- re-normalize mu (re-read from dout) -> XN chunks 0,1 ----
            {
                int row = tid >> 3, seg = (tid & 7) << 3;
                const float* mp = dout + (long)NB*320 + (row0 + row)*64 + seg;
                float4 a4 = *(const float4*)mp;
                float4 b4 = *(const float4*)(mp + 4);
                float2 st = *(const float2*)(sm + D_STATS + (row << 3));
                uint4 pk;
                pk.x = pack2((a4.x - st.x)*st.y, (a4.y - st.x)*st.y);
                pk.y = pack2((a4.z - st.x)*st.y, (a4.w - st.x)*st.y);
                pk.z = pack2((b4.x - st.x)*st.y, (b4.y - st.x)*st.y);
                pk.w = pack2((b4.z - st.x)*st.y, (b4.w - st.x)*st.y);
                int g0 = seg >> 3, c = g0 >> 2, gg = g0 & 3, sw = (row >> 1) & 3;
                *(uint4*)(sm + D_XN + c*CH64 + (row << 6) + ((gg ^ sw) << 4)) = pk;
            }
            __syncthreads();
        }
    }
}

// ---------------------------------------------------------------------------
extern "C" void kernel_launch(void* const* d_in, const int* in_sizes, int n_in,
                              void* d_out, int out_size, void* d_ws, size_t ws_size,
                              hipStream_t stream)
{
    (void)in_sizes; (void)n_in; (void)out_size; (void)ws_size;
    const float* curr = (const float*)d_in[0];
    const float* nxt  = (const float*)d_in[1];
    const float* eps  = (const float*)d_in[2];
    const float* ew1  = (const float*)d_in[3];
    const float* eb1  = (const float*)d_in[4];
    const float* ew2  = (const float*)d_in[5];
    const float* eb2  = (const float*)d_in[6];
    const float* muw  = (const float*)d_in[7];
    const float* mub  = (const float*)d_in[8];
    const float* lvw  = (const float*)d_in[9];
    const float* lvb  = (const float*)d_in[10];
    const float* gw1  = (const float*)d_in[11];
    const float* gb1  = (const float*)d_in[12];
    const float* gw2  = (const float*)d_in[13];
    const float* gb2  = (const float*)d_in[14];
    const float* gw3  = (const float*)d_in[15];
    const float* gb3  = (const float*)d_in[16];
    const float* w0 = (const float*)d_in[17]; const float* b0 = (const float*)d_in[18];
    const float* s0 = (const float*)d_in[19]; const float* t0 = (const float*)d_in[20];
    const float* w1 = (const float*)d_in[21]; const float* b1 = (const float*)d_in[22];
    const float* s1 = (const float*)d_in[23]; const float* t1 = (const float*)d_in[24];
    const float* w2 = (const float*)d_in[25]; const float* b2 = (const float*)d_in[26];
    const float* s2 = (const float*)d_in[27]; const float* t2 = (const float*)d_in[28];
    const float* w3 = (const float*)d_in[29]; const float* b3 = (const float*)d_in[30];
    const float* s3 = (const float*)d_in[31]; const float* t3 = (const float*)d_in[32];

    unsigned short* wsh = (unsigned short*)d_ws;
    float* bdec   = (float*)((char*)d_ws + WP_BDEC);
    float* coefws = (float*)((char*)d_ws + WP_COEF);
    float* dout   = (float*)d_out;

    hipLaunchKernelGGL(pack_small, dim3(996), dim3(256), 0, stream,
                       ew1, ew2, muw, lvw, gw1, gw2, gw3, wsh);
    hipLaunchKernelGGL(pack_dec, dim3(7680), dim3(256), 0, stream,
                       w0, w1, w2, w3, s0, s1, s2, s3, wsh);
    hipLaunchKernelGGL(pack_bdec, dim3(24), dim3(256), 0, stream,
                       w0, w1, w2, w3, b0, b1, b2, b3, t0, t1, t2, t3, bdec);
    hipLaunchKernelGGL(vae_enc, dim3(512), dim3(512), 0, stream,
                       curr, nxt, eps, eb1, eb2, mub, lvb, gb1, gb2, gb3,
                       wsh, coefws, dout);
    hipLaunchKernelGGL(vae_dec, dim3(1024), dim3(512), 0, stream,
                       curr, wsh, bdec, coefws, dout);
}

// Round 9
// 490.930 us; speedup vs baseline: 3.0133x; 3.0133x over previous
//
#include <hip/hip_runtime.h>
#include <hip/hip_bf16.h>
#include <stdint.h>

// ---------------------------------------------------------------------------
// MotionVAE, round 9: decoder = round-7 structure (known-good 400us, L2
// phase-locked) + ONE change: A-fragments prefetched one step ahead into
// named register buffers (aA/aB) inside the existing manual 2x interleave.
// Round-8's full unroll destroyed L2 phase-locking (FETCH 224MB -> 3.4GB);
// reverted. vae_enc unchanged.
// ---------------------------------------------------------------------------

#define NB 65536
#define CHUNK 8192   // enc activation chunk: [128][32] bf16
#define CH64  4096   // dec activation chunk: [64][32] bf16

typedef __attribute__((ext_vector_type(8))) short bf16x8;
typedef __attribute__((ext_vector_type(4))) float f32x4;

union FragU { bf16x8 v; unsigned int w[4]; uint4 u4; };

// ---- workspace byte offsets ----
#define WP_E1   0
#define WP_E2   262144
#define WP_MULV 393216
#define WP_G1   458752
#define WP_G2   499712
#define WP_G3   507904
#define WP_DEC  509952     // 4 x 6 x 10 x 16384 B
#define WP_BDEC 4442112    // f32 [4][6][256]
#define WP_COEF 4466688    // f32 [512 enc-blocks][768]

// ---- LDS offsets, encoder kernel (unchanged) ----
#define L_XN     0
#define L_SCR    81920
#define L_WB     98304
#define LDS_ENC  147456
#define L_MUF   (L_XN + 2*CHUNK)
#define L_LVF   L_WB
#define L_HG1   L_WB
#define L_HG2   (L_WB + 32768)
#define L_G2W   L_SCR
#define L_G3W   (L_SCR + 8192)
#define L_SCORE (L_SCR + 10240)

// ---- LDS offsets, decoder kernel (64-row) ----
#define D_XN     0          // 10 x 4096 = 40960
#define D_COEF   40960      // f32 [6][64] = 1536
#define D_STATS  42496      // f32 [64][2] = 512
#define D_PART   43008      // f32 [64][8][2] = 4096
#define D_PARTMU 47104      // f32 [64][8][2] = 4096
#define D_MUSTAT 51200      // f32 [64][2] = 512
#define LDS_DEC  51712

__device__ __forceinline__ unsigned int pack2(float a, float b){
    __hip_bfloat162 h = __float22bfloat162_rn(make_float2(a, b));
    union { __hip_bfloat162 h2; unsigned int u; } cv; cv.h2 = h; return cv.u;
}
__device__ __forceinline__ unsigned short f2bf(float a){
    __hip_bfloat16 h = __float2bfloat16(a);
    union { __hip_bfloat16 h1; unsigned short u; } cv; cv.h1 = h; return cv.u;
}
__device__ __forceinline__ float eluf(float x){ return x > 0.f ? x : expm1f(x); }
__device__ __forceinline__ f32x4 mfma16(bf16x8 a, bf16x8 b, f32x4 c){
    return __builtin_amdgcn_mfma_f32_16x16x32_bf16(a, b, c, 0, 0, 0);
}
__device__ __forceinline__ void gload16(const void* g, void* l){
    __builtin_amdgcn_global_load_lds(
        (__attribute__((address_space(1))) unsigned int*)(uintptr_t)g,
        (__attribute__((address_space(3))) unsigned int*)(unsigned int)(uintptr_t)l,
        16, 0, 0);
}

template<int N> __device__ __forceinline__ void pipeV(){
    __builtin_amdgcn_sched_barrier(0);
    asm volatile("s_waitcnt vmcnt(%0)" :: "n"(N) : "memory");
    asm volatile("s_barrier" ::: "memory");
    __builtin_amdgcn_sched_barrier(0);
}
template<int N> __device__ __forceinline__ void pipeVL(){
    __builtin_amdgcn_sched_barrier(0);
    asm volatile("s_waitcnt vmcnt(%0) lgkmcnt(0)" :: "n"(N) : "memory");
    asm volatile("s_barrier" ::: "memory");
    __builtin_amdgcn_sched_barrier(0);
}
__device__ __forceinline__ void pipeL(){
    __builtin_amdgcn_sched_barrier(0);
    asm volatile("s_waitcnt lgkmcnt(0)" ::: "memory");
    asm volatile("s_barrier" ::: "memory");
    __builtin_amdgcn_sched_barrier(0);
}

// ---------------------------------------------------------------------------
// pack kernels (unchanged)
// ---------------------------------------------------------------------------
__global__ void pack_small(const float* __restrict__ e1w, const float* __restrict__ e2w,
                           const float* __restrict__ muw, const float* __restrict__ lvw,
                           const float* __restrict__ g1w, const float* __restrict__ g2w,
                           const float* __restrict__ g3w, unsigned short* __restrict__ wsh){
    int p = blockIdx.x*256 + threadIdx.x;   // < 254976
    int local, k, n;
    auto decode = [&](int base, int NN){
        local = p - base;
        int i = local & 7, ln = (local>>3)&63, rest = local>>9;
        int ntg = rest % (NN/16), kb = rest / (NN/16);
        k = kb*32 + (ln>>4)*8 + i; n = ntg*16 + (ln&15);
    };
    if (p < 131072)      { decode(0,      256); wsh[WP_E1/2   + local] = f2bf(e1w[k*256+n]); }
    else if (p < 196608) { decode(131072, 256); wsh[WP_E2/2   + local] = f2bf(e2w[k*256+n]); }
    else if (p < 229376) { decode(196608, 128); wsh[WP_MULV/2 + local] = f2bf(n < 64 ? muw[k*64+n] : lvw[k*64+n-64]); }
    else if (p < 249856) { decode(229376,  64); wsh[WP_G1/2   + local] = f2bf(g1w[k*64+n]); }
    else if (p < 253952) { decode(249856,  64); wsh[WP_G2/2   + local] = f2bf(g2w[k*64+n]); }
    else                 { decode(253952,  16); wsh[WP_G3/2   + local] = f2bf(n < 6 ? g3w[k*6+n] : 0.f); }
}

__global__ void pack_dec(const float* __restrict__ w0, const float* __restrict__ w1,
                         const float* __restrict__ w2, const float* __restrict__ w3,
                         const float* __restrict__ s0, const float* __restrict__ s1,
                         const float* __restrict__ s2, const float* __restrict__ s3,
                         unsigned short* __restrict__ wsh){
    int p = blockIdx.x*256 + threadIdx.x;   // < 1966080
    int i = p & 7, ln = (p>>3)&63, rest = p>>9;
    int ntg = rest & 15, r2 = rest >> 4;
    int kb = r2 % 10, r3 = r2 / 10;
    int e = r3 % 6, L = r3 / 6;
    int k = kb*32 + (ln>>4)*8 + i;
    int n = ntg*16 + (ln&15);
    const float* w = (L==0)?w0:(L==1)?w1:(L==2)?w2:w3;
    const float* s = (L==0)?s0:(L==1)?s1:(L==2)?s2:s3;
    wsh[WP_DEC/2 + p] = f2bf(s[k] * w[(e*320+k)*256 + n]);
}

__global__ void pack_bdec(const float* __restrict__ w0, const float* __restrict__ w1,
                          const float* __restrict__ w2, const float* __restrict__ w3,
                          const float* __restrict__ b0, const float* __restrict__ b1,
                          const float* __restrict__ b2, const float* __restrict__ b3,
                          const float* __restrict__ t0, const float* __restrict__ t1,
                          const float* __restrict__ t2, const float* __restrict__ t3,
                          float* __restrict__ outp){
    int t = blockIdx.x*256 + threadIdx.x;   // < 6144
    int n = t & 255, r = t >> 8;
    int e = r % 6, L = r / 6;
    const float* w  = (L==0)?w0:(L==1)?w1:(L==2)?w2:w3;
    const float* b  = (L==0)?b0:(L==1)?b1:(L==2)?b2:b3;
    const float* lb = (L==0)?t0:(L==1)?t1:(L==2)?t2:t3;
    float acc = b[e*256 + n];
    for (int k = 0; k < 320; ++k) acc += lb[k] * w[(e*320+k)*256 + n];
    outp[(L*6+e)*256 + n] = acc;
}

// ---------------------------------------------------------------------------
// vae_enc (unchanged): encoder + reparam + gating.
// ---------------------------------------------------------------------------
__global__ __launch_bounds__(512, 2) void vae_enc(
    const float* __restrict__ curr, const float* __restrict__ nxt,
    const float* __restrict__ eps,
    const float* __restrict__ eb1, const float* __restrict__ eb2,
    const float* __restrict__ mub, const float* __restrict__ lvb,
    const float* __restrict__ gb1, const float* __restrict__ gb2,
    const float* __restrict__ gb3,
    const unsigned short* __restrict__ wsh,
    float* __restrict__ coefws, float* __restrict__ dout)
{
    __shared__ __align__(16) char sm[LDS_ENC];
    const int tid  = threadIdx.x;
    const int lane = tid & 63;
    const int wave = tid >> 6;
    const int wr   = wave >> 2;
    const int wc   = wave & 3;
    const int l15  = lane & 15;
    const int lh   = lane >> 4;
    const long row0 = (long)blockIdx.x * 128;
    const char* wsb = (const char*)wsh;
    const f32x4 Z4 = {0.f, 0.f, 0.f, 0.f};

    const int aswz = ((lh ^ ((l15 >> 1) & 3)) << 4);
    int aoff[4];
    #pragma unroll
    for (int mt = 0; mt < 4; ++mt)
        aoff[mt] = ((((wr << 6) + (mt << 4) + l15)) << 6) + aswz;

    auto WB = [&](int i) -> int { return L_WB + i*16384; };
    auto stage16 = [&](long gOff, int ldsBase){
        gload16(wsb + gOff + ((long)wave << 10) + (lane << 4), sm + ldsBase + (wave << 10));
        gload16(wsb + gOff + ((long)(wave + 8) << 10) + (lane << 4), sm + ldsBase + ((wave + 8) << 10));
    };
    auto stage8 = [&](long gOff, int ldsBase){
        gload16(wsb + gOff + ((long)wave << 10) + (lane << 4), sm + ldsBase + (wave << 10));
    };
    auto stage4 = [&](long gOff, int ldsBase){
        int u = wave & 3;
        gload16(wsb + gOff + ((long)u << 10) + (lane << 4), sm + ldsBase + (u << 10));
    };
    auto loadB = [&](int bufBase, int idx) -> bf16x8 {
        FragU f; f.u4 = *(const uint4*)(sm + bufBase + (idx << 10) + (lane << 4));
        return f.v;
    };
    auto putRow = [&](int base, int n, int mt, const f32x4& v){
        char* cb = sm + base + ((n >> 5) * CHUNK);
        int col = n & 31;
        #pragma unroll
        for (int j = 0; j < 4; ++j){
            int r = (wr << 6) + (mt << 4) + (lh << 2) + j;
            *(unsigned short*)(cb + (r << 6) + ((((col >> 3) ^ ((r >> 1) & 3))) << 4)
                               + ((col & 7) << 1)) = f2bf(v[j]);
        }
    };

    f32x4 acc4[4][4];
    // ===== encoder layer 1 =====
    #pragma unroll
    for (int a = 0; a < 4; ++a)
        #pragma unroll
        for (int b = 0; b < 4; ++b) acc4[a][b] = Z4;
    {
        const int xrow = tid >> 2, xg = tid & 3;
        float4 xa, xb;
        auto loadX = [&](int kb){
            const float* src = (kb < 8) ? curr : nxt;
            const float* p = src + (row0 + xrow)*256 + (kb & 7)*32 + xg*8;
            xa = *(const float4*)p; xb = *(const float4*)(p + 4);
        };
        auto packX = [&](int slot){
            uint4 pk;
            pk.x = pack2(xa.x, xa.y); pk.y = pack2(xa.z, xa.w);
            pk.z = pack2(xb.x, xb.y); pk.w = pack2(xb.z, xb.w);
            *(uint4*)(sm + L_XN + slot*CHUNK + (xrow << 6)
                      + ((xg ^ ((xrow >> 1) & 3)) << 4)) = pk;
        };
        stage16(WP_E1, WB(0)); stage16(WP_E1 + 16384, WB(1));
        loadX(0); packX(0);
        loadX(1);
        #pragma unroll 1
        for (int s = 0; s < 16; ++s){
            pipeVL<4>();
            if (s + 2 < 16) stage16(WP_E1 + (long)(s + 2)*16384, WB((s + 2) % 3));
            if (s + 1 < 16){
                packX((s + 1) & 1);
                if (s + 2 < 16) loadX(s + 2);
            }
            int xbuf = L_XN + (s & 1)*CHUNK;
            int wb = WB(s % 3);
            FragU a[4];
            #pragma unroll
            for (int mt = 0; mt < 4; ++mt) a[mt].u4 = *(const uint4*)(sm + xbuf + aoff[mt]);
            #pragma unroll
            for (int nt = 0; nt < 4; ++nt){
                bf16x8 b = loadB(wb, wc*4 + nt);
                #pragma unroll
                for (int mt = 0; mt < 4; ++mt) acc4[mt][nt] = mfma16(a[mt].v, b, acc4[mt][nt]);
            }
        }
        pipeL();
        #pragma unroll
        for (int nt = 0; nt < 4; ++nt){
            int n = wc*64 + nt*16 + l15;
            float bias = eb1[n];
            #pragma unroll
            for (int mt = 0; mt < 4; ++mt){
                f32x4 v;
                #pragma unroll
                for (int j = 0; j < 4; ++j) v[j] = eluf(acc4[mt][nt][j] + bias);
                putRow(L_XN, n, mt, v);
            }
        }
        stage16(WP_E2, WB(0)); stage16(WP_E2 + 16384, WB(1));
        pipeL();
    }
    // ===== encoder layer 2 =====
    #pragma unroll
    for (int a = 0; a < 4; ++a)
        #pragma unroll
        for (int b = 0; b < 4; ++b) acc4[a][b] = Z4;
    {
        #pragma unroll 1
        for (int s = 0; s < 8; ++s){
            if (s + 1 < 8) pipeV<2>(); else pipeV<0>();
            if (s + 2 < 8) stage16(WP_E2 + (long)(s + 2)*16384, WB((s + 2) % 3));
            int wb = WB(s % 3);
            FragU a[4];
            #pragma unroll
            for (int mt = 0; mt < 4; ++mt)
                a[mt].u4 = *(const uint4*)(sm + L_XN + s*CHUNK + aoff[mt]);
            #pragma unroll
            for (int nt = 0; nt < 4; ++nt){
                bf16x8 b = loadB(wb, wc*4 + nt);
                #pragma unroll
                for (int mt = 0; mt < 4; ++mt) acc4[mt][nt] = mfma16(a[mt].v, b, acc4[mt][nt]);
            }
        }
        pipeL();
        #pragma unroll
        for (int nt = 0; nt < 4; ++nt){
            int n = wc*64 + nt*16 + l15;
            float bias = eb2[n];
            #pragma unroll
            for (int mt = 0; mt < 4; ++mt){
                f32x4 v;
                #pragma unroll
                for (int j = 0; j < 4; ++j) v[j] = eluf(acc4[mt][nt][j] + bias);
                putRow(L_XN, n, mt, v);
            }
        }
        stage8(WP_MULV, WB(0)); stage8(WP_MULV + 8192, WB(1));
        pipeL();
    }
    // ===== mu | logvar =====
    {
        f32x4 am[4][2];
        #pragma unroll
        for (int a = 0; a < 4; ++a){ am[a][0] = Z4; am[a][1] = Z4; }
        #pragma unroll 1
        for (int s = 0; s < 8; ++s){
            if (s + 1 < 8) pipeV<1>(); else pipeV<0>();
            if (s + 2 < 8) stage8(WP_MULV + (long)(s + 2)*8192, WB((s + 2) % 3));
            int wb = WB(s % 3);
            FragU a[4];
            #pragma unroll
            for (int mt = 0; mt < 4; ++mt)
                a[mt].u4 = *(const uint4*)(sm + L_XN + s*CHUNK + aoff[mt]);
            #pragma unroll
            for (int nt = 0; nt < 2; ++nt){
                bf16x8 b = loadB(wb, wc*2 + nt);
                #pragma unroll
                for (int mt = 0; mt < 4; ++mt) am[mt][nt] = mfma16(a[mt].v, b, am[mt][nt]);
            }
        }
        pipeL();
        #pragma unroll
        for (int nt = 0; nt < 2; ++nt){
            int n = wc*32 + nt*16 + l15;
            if (n < 64){
                float bias = mub[n];
                #pragma unroll
                for (int mt = 0; mt < 4; ++mt)
                    #pragma unroll
                    for (int j = 0; j < 4; ++j){
                        int r = (wr << 6) + (mt << 4) + (lh << 2) + j;
                        float v = am[mt][nt][j] + bias;
                        *(float*)(sm + L_MUF + (r << 8) + (n << 2)) = v;
                        dout[(long)NB*320 + (row0 + r)*64 + n] = v;
                    }
            } else {
                float bias = lvb[n - 64];
                #pragma unroll
                for (int mt = 0; mt < 4; ++mt)
                    #pragma unroll
                    for (int j = 0; j < 4; ++j){
                        int r = (wr << 6) + (mt << 4) + (lh << 2) + j;
                        float v = am[mt][nt][j] + bias;
                        *(float*)(sm + L_LVF + (r << 8) + ((n - 64) << 2)) = v;
                        dout[(long)NB*384 + (row0 + r)*64 + (n - 64)] = v;
                    }
            }
        }
        pipeL();
    }
    // ===== z =====
    {
        int row = tid >> 2, seg = (tid & 3) << 4;
        float zm[16], zl[16];
        #pragma unroll
        for (int q = 0; q < 4; ++q){
            float4 m4 = *(const float4*)(sm + L_MUF + (row << 8) + ((seg + q*4) << 2));
            float4 l4 = *(const float4*)(sm + L_LVF + (row << 8) + ((seg + q*4) << 2));
            zm[q*4+0]=m4.x; zm[q*4+1]=m4.y; zm[q*4+2]=m4.z; zm[q*4+3]=m4.w;
            zl[q*4+0]=l4.x; zl[q*4+1]=l4.y; zl[q*4+2]=l4.z; zl[q*4+3]=l4.w;
        }
        const float* ep = eps + (row0 + row)*64 + seg;
        float* zo = dout + (long)NB*256 + (row0 + row)*64 + seg;
        #pragma unroll
        for (int q = 0; q < 4; ++q){
            float4 e4 = *(const float4*)(ep + q*4);
            float4 z4;
            z4.x = zm[q*4+0] + e4.x * expf(0.5f*zl[q*4+0]);
            z4.y = zm[q*4+1] + e4.y * expf(0.5f*zl[q*4+1]);
            z4.z = zm[q*4+2] + e4.z * expf(0.5f*zl[q*4+2]);
            z4.w = zm[q*4+3] + e4.w * expf(0.5f*zl[q*4+3]);
            *(float4*)(zo + q*4) = z4;
        }
        uint4 pkA, pkB;
        pkA.x = pack2(zm[0],  zm[1]);  pkA.y = pack2(zm[2],  zm[3]);
        pkA.z = pack2(zm[4],  zm[5]);  pkA.w = pack2(zm[6],  zm[7]);
        pkB.x = pack2(zm[8],  zm[9]);  pkB.y = pack2(zm[10], zm[11]);
        pkB.z = pack2(zm[12], zm[13]); pkB.w = pack2(zm[14], zm[15]);
        int c = seg >> 5, g0 = (seg & 31) >> 3, sw = (row >> 1) & 3;
        char* cb = sm + L_XN + c*CHUNK + (row << 6);
        *(uint4*)(cb + ((g0 ^ sw) << 4))       = pkA;
        *(uint4*)(cb + (((g0 + 1) ^ sw) << 4)) = pkB;
    }
    pipeL();
    // ===== curr -> XN chunks 2..9; G1 prologue =====
    #pragma unroll
    for (int c = 0; c < 2; ++c){
        int idx = c*512 + tid;
        int row = idx & 127, kbi = idx >> 7;
        const float* p = curr + (row0 + row)*256 + kbi*32;
        char* cb = sm + L_XN + (2 + kbi)*CHUNK + (row << 6);
        int sw = (row >> 1) & 3;
        #pragma unroll
        for (int g = 0; g < 4; ++g){
            float4 fa = *(const float4*)(p + g*8);
            float4 fb = *(const float4*)(p + g*8 + 4);
            uint4 pk;
            pk.x = pack2(fa.x, fa.y); pk.y = pack2(fa.z, fa.w);
            pk.z = pack2(fb.x, fb.y); pk.w = pack2(fb.z, fb.w);
            *(uint4*)(cb + ((g ^ sw) << 4)) = pk;
        }
    }
    stage4(WP_G1, WB(0)); stage4(WP_G1 + 4096, WB(1));
    pipeL();
    // ===== gating MLP =====
    {
        f32x4 ga[4];
        #pragma unroll
        for (int a = 0; a < 4; ++a) ga[a] = Z4;
        #pragma unroll 1
        for (int s = 0; s < 10; ++s){
            if (s + 1 < 10) pipeV<1>(); else pipeV<0>();
            if (s + 2 < 10) stage4(WP_G1 + (long)(s + 2)*4096, WB((s + 2) % 3));
            int wb = WB(s % 3);
            bf16x8 b = loadB(wb, wc);
            #pragma unroll
            for (int mt = 0; mt < 4; ++mt){
                FragU a; a.u4 = *(const uint4*)(sm + L_XN + s*CHUNK + aoff[mt]);
                ga[mt] = mfma16(a.v, b, ga[mt]);
            }
        }
        pipeL();
        {
            int n = wc*16 + l15;
            float bias = gb1[n];
            #pragma unroll
            for (int mt = 0; mt < 4; ++mt){
                f32x4 v;
                #pragma unroll
                for (int j = 0; j < 4; ++j) v[j] = eluf(ga[mt][j] + bias);
                putRow(L_HG1, n, mt, v);
            }
        }
        stage8(WP_G2, L_G2W);
        if (wave < 2)
            gload16(wsb + WP_G3 + ((long)wave << 10) + (lane << 4),
                    sm + L_G3W + (wave << 10));
        pipeVL<0>();
        // G2
        #pragma unroll
        for (int a = 0; a < 4; ++a) ga[a] = Z4;
        #pragma unroll
        for (int kb = 0; kb < 2; ++kb){
            bf16x8 b = loadB(L_G2W, kb*4 + wc);
            #pragma unroll
            for (int mt = 0; mt < 4; ++mt){
                FragU a; a.u4 = *(const uint4*)(sm + L_HG1 + kb*CHUNK + aoff[mt]);
                ga[mt] = mfma16(a.v, b, ga[mt]);
            }
        }
        pipeL();
        {
            int n = wc*16 + l15;
            float bias = gb2[n];
            #pragma unroll
            for (int mt = 0; mt < 4; ++mt){
                f32x4 v;
                #pragma unroll
                for (int j = 0; j < 4; ++j) v[j] = eluf(ga[mt][j] + bias);
                putRow(L_HG2, n, mt, v);
            }
        }
        pipeL();
        // G3
        if (wc == 0){
            f32x4 sc[4];
            #pragma unroll
            for (int a = 0; a < 4; ++a) sc[a] = Z4;
            #pragma unroll
            for (int kb = 0; kb < 2; ++kb){
                bf16x8 b = loadB(L_G3W, kb);
                #pragma unroll
                for (int mt = 0; mt < 4; ++mt){
                    FragU a; a.u4 = *(const uint4*)(sm + L_HG2 + kb*CHUNK + aoff[mt]);
                    sc[mt] = mfma16(a.v, b, sc[mt]);
                }
            }
            if (l15 < 8){
                float bias = (l15 < 6) ? gb3[l15] : 0.f;
                #pragma unroll
                for (int mt = 0; mt < 4; ++mt)
                    #pragma unroll
                    for (int j = 0; j < 4; ++j){
                        int r = (wr << 6) + (mt << 4) + (lh << 2) + j;
                        *(float*)(sm + L_SCORE + (r << 5) + (l15 << 2)) = sc[mt][j] + bias;
                    }
            }
        }
        pipeL();
        if (tid < 128){
            float s[6];
            #pragma unroll
            for (int e = 0; e < 6; ++e) s[e] = *(const float*)(sm + L_SCORE + (tid << 5) + (e << 2));
            float m = s[0];
            #pragma unroll
            for (int e = 1; e < 6; ++e) m = fmaxf(m, s[e]);
            float sum = 0.f;
            #pragma unroll
            for (int e = 0; e < 6; ++e){ s[e] = expf(s[e] - m); sum += s[e]; }
            float inv = 1.f / sum;
            float* cw = coefws + (long)blockIdx.x * 768;
            #pragma unroll
            for (int e = 0; e < 6; ++e) cw[e*128 + tid] = s[e] * inv;
        }
    }
}

// ---------------------------------------------------------------------------
// vae_dec: 64-row blocks x 512 threads (8 waves), wave w owns 64 rows x
// 32 cols. Round-7 barrier-free interleave + A-prefetch into named regs.
// ---------------------------------------------------------------------------
__global__ __launch_bounds__(512, 4) void vae_dec(
    const float* __restrict__ curr,
    const unsigned short* __restrict__ wsh, const float* __restrict__ bdec,
    const float* __restrict__ coefws, float* __restrict__ dout)
{
    __shared__ __align__(16) char sm[LDS_DEC];
    const int tid  = threadIdx.x;
    const int lane = tid & 63;
    const int w    = tid >> 6;          // 0..7 column group (32 cols)
    const int l15  = lane & 15;
    const int lh   = lane >> 4;
    const long row0 = (long)blockIdx.x * 64;
    const int eb   = blockIdx.x >> 1, half = blockIdx.x & 1;
    const char* wsb = (const char*)wsh;
    const f32x4 Z4 = {0.f, 0.f, 0.f, 0.f};

    const int aswz = ((lh ^ ((l15 >> 1) & 3)) << 4);
    int aoff[4];
    #pragma unroll
    for (int mt = 0; mt < 4; ++mt)
        aoff[mt] = (((mt << 4) + l15) << 6) + aswz;

    auto putRow = [&](int base, int n, int mt, const f32x4& v){
        char* cb = sm + base + ((n >> 5) * CH64);
        int col = n & 31;
        #pragma unroll
        for (int j = 0; j < 4; ++j){
            int r = (mt << 4) + (lh << 2) + j;
            *(unsigned short*)(cb + (r << 6) + ((((col >> 3) ^ ((r >> 1) & 3))) << 4)
                               + ((col & 7) << 1)) = f2bf(v[j]);
        }
    };

    // ---- coef: [6][64] for this block's row half ----
    if (tid < 384)
        *(float*)(sm + D_COEF + (tid << 2)) =
            coefws[(long)eb*768 + (tid >> 6)*128 + half*64 + (tid & 63)];
    // ---- raw mu (f32 in dout) -> XN chunks 0,1 ----
    {
        int row = tid >> 3, seg = (tid & 7) << 3;
        const float* mp = dout + (long)NB*320 + (row0 + row)*64 + seg;
        float4 a4 = *(const float4*)mp;
        float4 b4 = *(const float4*)(mp + 4);
        uint4 pk;
        pk.x = pack2(a4.x, a4.y); pk.y = pack2(a4.z, a4.w);
        pk.z = pack2(b4.x, b4.y); pk.w = pack2(b4.z, b4.w);
        int g0 = seg >> 3, c = g0 >> 2, gg = g0 & 3, sw = (row >> 1) & 3;
        *(uint4*)(sm + D_XN + c*CH64 + (row << 6) + ((gg ^ sw) << 4)) = pk;
    }
    // ---- curr -> XN chunks 2..9 ----
    {
        int row = tid & 63, kbi = tid >> 6;
        const float* p = curr + (row0 + row)*256 + kbi*32;
        char* cb = sm + D_XN + (2 + kbi)*CH64 + (row << 6);
        int sw = (row >> 1) & 3;
        #pragma unroll
        for (int g = 0; g < 4; ++g){
            float4 fa = *(const float4*)(p + g*8);
            float4 fb = *(const float4*)(p + g*8 + 4);
            uint4 pk;
            pk.x = pack2(fa.x, fa.y); pk.y = pack2(fa.z, fa.w);
            pk.z = pack2(fb.x, fb.y); pk.w = pack2(fb.z, fb.w);
            *(uint4*)(cb + ((g ^ sw) << 4)) = pk;
        }
    }
    __syncthreads();
    // ---- layer-0 LN stats ----
    {
        int row = tid >> 3, part = tid & 7;
        int sw = (row >> 1) & 3;
        float s = 0.f, q = 0.f, smu = 0.f, qmu = 0.f;
        #pragma unroll
        for (int k = 0; k < 5; ++k){
            int g = part + (k << 3);
            int c = g >> 2, gg = g & 3;
            uint4 d = *(const uint4*)(sm + D_XN + c*CH64 + (row << 6) + ((gg ^ sw) << 4));
            const unsigned int* dw = (const unsigned int*)&d;
            float ls = 0.f, lq = 0.f;
            #pragma unroll
            for (int u = 0; u < 4; ++u){
                float lo = __uint_as_float(dw[u] << 16);
                float hi = __uint_as_float(dw[u] & 0xffff0000u);
                ls += lo + hi; lq += lo*lo + hi*hi;
            }
            s += ls; q += lq;
            if (k == 0){ smu = ls; qmu = lq; }
        }
        *(float2*)(sm + D_PART   + (((row << 3) + part) << 3)) = make_float2(s, q);
        *(float2*)(sm + D_PARTMU + (((row << 3) + part) << 3)) = make_float2(smu, qmu);
    }
    __syncthreads();
    if (tid < 64){
        float S = 0.f, Q = 0.f, Sm = 0.f, Qm = 0.f;
        #pragma unroll
        for (int pp = 0; pp < 8; ++pp){
            float2 f = *(const float2*)(sm + D_PART   + (((tid << 3) + pp) << 3));
            float2 g = *(const float2*)(sm + D_PARTMU + (((tid << 3) + pp) << 3));
            S += f.x; Q += f.y; Sm += g.x; Qm += g.y;
        }
        float mean = S * (1.f/320.f);
        float var  = Q * (1.f/320.f) - mean*mean;
        *(float2*)(sm + D_STATS  + (tid << 3)) = make_float2(mean, rsqrtf(var + 1e-5f));
        *(float2*)(sm + D_MUSTAT + (tid << 3)) = make_float2(Sm, Qm);
    }
    __syncthreads();
    {   // normalize all 10 chunks in place
        int row = tid >> 3, part = tid & 7;
        int sw = (row >> 1) & 3;
        float2 st = *(const float2*)(sm + D_STATS + (row << 3));
        #pragma unroll
        for (int k = 0; k < 5; ++k){
            int g = part + (k << 3);
            int c = g >> 2, gg = g & 3;
            char* p = sm + D_XN + c*CH64 + (row << 6) + ((gg ^ sw) << 4);
            uint4 d = *(const uint4*)p;
            const unsigned int* dw = (const unsigned int*)&d;
            uint4 o; unsigned int* ow = (unsigned int*)&o;
            #pragma unroll
            for (int u = 0; u < 4; ++u){
                float lo = (__uint_as_float(dw[u] << 16)         - st.x) * st.y;
                float hi = (__uint_as_float(dw[u] & 0xffff0000u) - st.x) * st.y;
                ow[u] = pack2(lo, hi);
            }
            *(uint4*)p = o;
        }
    }
    __syncthreads();

    // ---- 4 MoE layers, barrier-free inner loop ----
    f32x4 master[4][2], acc[4][2];
    #pragma unroll
    for (int a = 0; a < 4; ++a){ master[a][0] = Z4; master[a][1] = Z4; }

    #pragma unroll 1
    for (int L = 0; L < 4; ++L){
        const char* wLb = wsb + WP_DEC + (((long)L*60) << 14) + (lane << 4)
                          + ((w*2) << 10);
        FragU bA[2], bB[2], aA[4], aB[4];
        auto loadBG = [&](FragU* bd, int s){
            const char* p = wLb + ((long)s << 14);
            bd[0].u4 = *(const uint4*)p;
            bd[1].u4 = *(const uint4*)(p + 1024);
        };
        auto loadA = [&](FragU* ad, int kb){
            #pragma unroll
            for (int mt = 0; mt < 4; ++mt)
                ad[mt].u4 = *(const uint4*)(sm + D_XN + kb*CH64 + aoff[mt]);
        };
        auto doStep = [&](FragU* bd, FragU* ad, int s){
            int e  = s / 10;
            int kb = s - e*10;
            if (kb == 0){
                #pragma unroll
                for (int x = 0; x < 4; ++x){ acc[x][0] = Z4; acc[x][1] = Z4; }
            }
            #pragma unroll
            for (int nt = 0; nt < 2; ++nt)
                #pragma unroll
                for (int mt = 0; mt < 4; ++mt)
                    acc[mt][nt] = mfma16(ad[mt].v, bd[nt].v, acc[mt][nt]);
            if (kb == 9){
                #pragma unroll
                for (int mt = 0; mt < 4; ++mt){
                    f32x4 cq = *(const f32x4*)(sm + D_COEF +
                                ((e*64 + (mt << 4) + (lh << 2)) << 2));
                    #pragma unroll
                    for (int nt = 0; nt < 2; ++nt)
                        #pragma unroll
                        for (int j = 0; j < 4; ++j)
                            master[mt][nt][j] = fmaf(cq[j], acc[mt][nt][j], master[mt][nt][j]);
                }
            }
        };
        loadBG(bA, 0);
        loadA(aA, 0);
        #pragma unroll 1
        for (int s = 0; s < 60; s += 2){
            int e1 = (s + 1) / 10;
            loadBG(bB, s + 1);
            loadA(aB, (s + 1) - e1*10);
            doStep(bA, aA, s);
            if (s + 2 < 60){
                int e2 = (s + 2) / 10;
                loadBG(bA, s + 2);
                loadA(aA, (s + 2) - e2*10);
            }
            doStep(bB, aB, s + 1);
        }
        __syncthreads();   // all waves done reading XN before rewrite

        // ---- epilogue ----
        {
            float bv[6][2];
            #pragma unroll
            for (int ee = 0; ee < 6; ++ee)
                #pragma unroll
                for (int nt = 0; nt < 2; ++nt)
                    bv[ee][nt] = bdec[((L*6 + ee) << 8) + w*32 + nt*16 + l15];
            #pragma unroll
            for (int mt = 0; mt < 4; ++mt){
                f32x4 cq[6];
                #pragma unroll
                for (int ee = 0; ee < 6; ++ee)
                    cq[ee] = *(const f32x4*)(sm + D_COEF +
                              ((ee*64 + (mt << 4) + (lh << 2)) << 2));
                #pragma unroll
                for (int nt = 0; nt < 2; ++nt){
                    int n = w*32 + nt*16 + l15;
                    f32x4 v;
                    #pragma unroll
                    for (int j = 0; j < 4; ++j){
                        float bias = cq[0][j]*bv[0][nt] + cq[1][j]*bv[1][nt]
                                   + cq[2][j]*bv[2][nt] + cq[3][j]*bv[3][nt]
                                   + cq[4][j]*bv[4][nt] + cq[5][j]*bv[5][nt];
                        float mix = master[mt][nt][j] + bias;
                        v[j] = (L == 3) ? mix : eluf(mix);
                    }
                    if (L < 3){
                        acc[mt][nt] = v;
                        master[mt][nt] = (L < 2) ? v : Z4;
                    } else {
                        #pragma unroll
                        for (int j = 0; j < 4; ++j){
                            int r = (mt << 4) + (lh << 2) + j;
                            dout[(row0 + r)*256 + n] = v[j];
                        }
                    }
                }
            }
        }
        if (L < 3){
            // ---- next-layer LN stats: shuffle reduce over out tile ----
            #pragma unroll
            for (int mt = 0; mt < 4; ++mt){
                f32x4 sv = acc[mt][0] + acc[mt][1];
                f32x4 qv = acc[mt][0]*acc[mt][0] + acc[mt][1]*acc[mt][1];
                #pragma unroll
                for (int x = 1; x < 16; x <<= 1){
                    #pragma unroll
                    for (int j = 0; j < 4; ++j){
                        sv[j] += __shfl_xor(sv[j], x);
                        qv[j] += __shfl_xor(qv[j], x);
                    }
                }
                if (l15 == 0){
                    #pragma unroll
                    for (int j = 0; j < 4; ++j){
                        int r = (mt << 4) + (lh << 2) + j;
                        *(float2*)(sm + D_PART + (((r << 3) + w) << 3)) = make_float2(sv[j], qv[j]);
                    }
                }
            }
            __syncthreads();
            if (tid < 64){
                float2 mu2 = *(const float2*)(sm + D_MUSTAT + (tid << 3));
                float S = mu2.x, Q = mu2.y;
                #pragma unroll
                for (int pp = 0; pp < 8; ++pp){
                    float2 f = *(const float2*)(sm + D_PART + (((tid << 3) + pp) << 3));
                    S += f.x; Q += f.y;
                }
                float mean = S * (1.f/320.f);
                float var  = Q * (1.f/320.f) - mean*mean;
                *(float2*)(sm + D_STATS + (tid << 3)) = make_float2(mean, rsqrtf(var + 1e-5f));
            }
            __syncthreads();
            // ---- write normalized out -> XN chunks 2..9 (from registers) ----
            #pragma unroll
            for (int mt = 0; mt < 4; ++mt){
                int r0 = (mt << 4) + (lh << 2);
                float4 p0 = *(const float4*)(sm + D_STATS + (r0 << 3));
                float4 p1 = *(const float4*)(sm + D_STATS + (r0 << 3) + 16);
                float mj[4] = {p0.x, p0.z, p1.x, p1.z};
                float rj[4] = {p0.y, p0.w, p1.y, p1.w};
                #pragma unroll
                for (int nt = 0; nt < 2; ++nt){
                    int n = w*32 + nt*16 + l15;
                    f32x4 xn;
                    #pragma unroll
                    for (int j = 0; j < 4; ++j) xn[j] = (acc[mt][nt][j] - mj[j]) * rj[j];
                    putRow(D_XN + 2*CH64, n, mt, xn);
                }
            }
            // ---- re-normalize mu (re-read from dout) -> XN chunks 0,1 ----
            {
                int row = tid >> 3, seg = (tid & 7) << 3;
                const float* mp = dout + (long)NB*320 + (row0 + row)*64 + seg;
                float4 a4 = *(const float4*)mp;
                float4 b4 = *(const float4*)(mp + 4);
                float2 st = *(const float2*)(sm + D_STATS + (row << 3));
                uint4 pk;
                pk.x = pack2((a4.x - st.x)*st.y, (a4.y - st.x)*st.y);
                pk.y = pack2((a4.z - st.x)*st.y, (a4.w - st.x)*st.y);
                pk.z = pack2((b4.x - st.x)*st.y, (b4.y - st.x)*st.y);
                pk.w = pack2((b4.z - st.x)*st.y, (b4.w - st.x)*st.y);
                int g0 = seg >> 3, c = g0 >> 2, gg = g0 & 3, sw = (row >> 1) & 3;
                *(uint4*)(sm + D_XN + c*CH64 + (row << 6) + ((gg ^ sw) << 4)) = pk;
            }
            __syncthreads();
        }
    }
}

// ---------------------------------------------------------------------------
extern "C" void kernel_launch(void* const* d_in, const int* in_sizes, int n_in,
                              void* d_out, int out_size, void* d_ws, size_t ws_size,
                              hipStream_t stream)
{
    (void)in_sizes; (void)n_in; (void)out_size; (void)ws_size;
    const float* curr = (const float*)d_in[0];
    const float* nxt  = (const float*)d_in[1];
    const float* eps  = (const float*)d_in[2];
    const float* ew1  = (const float*)d_in[3];
    const float* eb1  = (const float*)d_in[4];
    const float* ew2  = (const float*)d_in[5];
    const float* eb2  = (const float*)d_in[6];
    const float* muw  = (const float*)d_in[7];
    const float* mub  = (const float*)d_in[8];
    const float* lvw  = (const float*)d_in[9];
    const float* lvb  = (const float*)d_in[10];
    const float* gw1  = (const float*)d_in[11];
    const float* gb1  = (const float*)d_in[12];
    const float* gw2  = (const float*)d_in[13];
    const float* gb2  = (const float*)d_in[14];
    const float* gw3  = (const float*)d_in[15];
    const float* gb3  = (const float*)d_in[16];
    const float* w0 = (const float*)d_in[17]; const float* b0 = (const float*)d_in[18];
    const float* s0 = (const float*)d_in[19]; const float* t0 = (const float*)d_in[20];
    const float* w1 = (const float*)d_in[21]; const float* b1 = (const float*)d_in[22];
    const float* s1 = (const float*)d_in[23]; const float* t1 = (const float*)d_in[24];
    const float* w2 = (const float*)d_in[25]; const float* b2 = (const float*)d_in[26];
    const float* s2 = (const float*)d_in[27]; const float* t2 = (const float*)d_in[28];
    const float* w3 = (const float*)d_in[29]; const float* b3 = (const float*)d_in[30];
    const float* s3 = (const float*)d_in[31]; const float* t3 = (const float*)d_in[32];

    unsigned short* wsh = (unsigned short*)d_ws;
    float* bdec   = (float*)((char*)d_ws + WP_BDEC);
    float* coefws = (float*)((char*)d_ws + WP_COEF);
    float* dout   = (float*)d_out;

    hipLaunchKernelGGL(pack_small, dim3(996), dim3(256), 0, stream,
                       ew1, ew2, muw, lvw, gw1, gw2, gw3, wsh);
    hipLaunchKernelGGL(pack_dec, dim3(7680), dim3(256), 0, stream,
                       w0, w1, w2, w3, s0, s1, s2, s3, wsh);
    hipLaunchKernelGGL(pack_bdec, dim3(24), dim3(256), 0, stream,
                       w0, w1, w2, w3, b0, b1, b2, b3, t0, t1, t2, t3, bdec);
    hipLaunchKernelGGL(vae_enc, dim3(512), dim3(512), 0, stream,
                       curr, nxt, eps, eb1, eb2, mub, lvb, gb1, gb2, gb3,
                       wsh, coefws, dout);
    hipLaunchKernelGGL(vae_dec, dim3(1024), dim3(512), 0, stream,
                       curr, wsh, bdec, coefws, dout);
}